// Round 5
// baseline (154.717 us; speedup 1.0000x reference)
//
#include <hip/hip_runtime.h>
#include <math.h>

// ---------------- problem constants ----------------
constexpr float C_CURV = 0.1f;
constexpr float SQRT_C = 0.31622776601683794f;        // sqrt(0.1)

constexpr int N_GENUS   = 60;
constexpr int N_SPECIES = 4096;
constexpr int NB        = 1024;   // batch
constexpr int EMB       = 64;

// ---------------- workspace layout (floats) ----------------
constexpr int OFF_HYP_S = 0;                               // 4096*64 fp32 (genus branch reads)
constexpr int OFF_HYP_G = OFF_HYP_S + N_SPECIES * EMB;     // 60*64
constexpr int OFF_S2    = OFF_HYP_G + N_GENUS * EMB;       // 4096
constexpr int OFF_G2    = OFF_S2 + N_SPECIES;              // 64 (60 used)
constexpr int OFF_X2    = OFF_G2 + 64;                     // 1024
constexpr int OFF_CNT   = OFF_X2 + NB;                     // 1 int: #present species (= nvs)
constexpr int OFF_NVG   = OFF_CNT + 1;                     // 1 float: #valid genera
constexpr int OFF_SPART = OFF_CNT + 2;                     // 1024 float2 partials (species blocks)
constexpr int OFF_GPART = OFF_SPART + 2 * NB;              // 1024 float2 partials (genus items)
constexpr int OFF_LIST  = OFF_GPART + 2 * NB;              // 1024 ints compact present list
// done-counters: 64 group counters spread 64B apart + 1 level-2 counter
constexpr int OFF_CTR   = OFF_LIST + NB;                   // 65*16 ints
// bf16 copies, padded row stride 72 (16B-aligned rows; stride = 9x16B)
constexpr int OFF_XBF   = ((OFF_CTR + 65 * 16 + 3) / 4) * 4;   // 1024*72 ushort
constexpr int OFF_SBF   = OFF_XBF + NB * 72 / 2;               // 4096*72 ushort
constexpr int BFSTRIDE  = 72;                              // ushorts per row

typedef short  bf16x8 __attribute__((ext_vector_type(8)));
typedef float  f32x4  __attribute__((ext_vector_type(4)));

// ---------------- helpers ----------------
__device__ __forceinline__ float wave_sum(float v) {
    #pragma unroll
    for (int off = 32; off; off >>= 1) v += __shfl_xor(v, off);
    return v;
}

__device__ __forceinline__ unsigned short f2bf(float f) {   // RNE f32 -> bf16
    unsigned int u = __builtin_bit_cast(unsigned int, f);
    u += 0x7FFFu + ((u >> 16) & 1u);
    return (unsigned short)(u >> 16);
}

// d = 2/sqrt(c)*atanh(arg); sp_neg = softplus(-d). u=(1-arg)/(1+arg), L=log2(u):
// d = -(ln2/sqrt(c))*L, exp(-d) = exp2(L/sqrt(c)). Native HW transcendentals only.
__device__ __forceinline__ void pair_terms(float dot_ay, float a2, float y2,
                                           float& d, float& sp_neg) {
    float ca   = fmaf(2.0f * C_CURV, dot_ay, fmaf(C_CURV, y2, 1.0f));
    float cy   = fmaf(-C_CURV, a2, 1.0f);
    float num2 = fmaf(ca * ca, a2, fmaf(2.0f * ca * cy, dot_ay, cy * cy * y2));
    float den  = fmaf(2.0f * C_CURV, dot_ay, fmaf(C_CURV * C_CURV, a2 * y2, 1.0f));
    float arg  = SQRT_C * __builtin_amdgcn_sqrtf(fmaxf(num2, 0.0f))
                        * __builtin_amdgcn_rcpf(fmaxf(fabsf(den), 1e-15f));
    arg = fminf(arg, 1.0f - 1e-5f);
    float u = (1.0f - arg) * __builtin_amdgcn_rcpf(1.0f + arg);
    float L = __builtin_amdgcn_logf(u);                    // log2(u) <= 0
    d       = -2.19201176f * L;
    float e = __builtin_amdgcn_exp2f(3.16227766f * L);     // exp(-d)
    sp_neg  = 0.69314718f * __builtin_amdgcn_logf(1.0f + e);
}

// ---------------- K1: fused prep ----------------
// blocks 0..1294: projection waves; block 1295: mask/list/counts + counter zeroing
__global__ __launch_bounds__(256) void k_prep(
    const float* __restrict__ X, const int* __restrict__ Ts,
    const int* __restrict__ s2g, const float* __restrict__ gp,
    const float* __restrict__ sp, float* __restrict__ ws)
{
    __shared__ unsigned char pres[N_SPECIES];
    __shared__ unsigned char gm[64];
    __shared__ int scnt, gcnt;

    int t = threadIdx.x;
    unsigned short* xbf = (unsigned short*)(ws + OFF_XBF);
    unsigned short* sbf = (unsigned short*)(ws + OFF_SBF);

    if (blockIdx.x == 1295) {           // ---- mask block ----
        int* wsI = (int*)ws;
        for (int i = t; i < 65 * 16; i += 256) wsI[OFF_CTR + i] = 0;  // zero done-counters
        for (int s = t; s < N_SPECIES; s += 256) pres[s] = 0;
        if (t < 64) gm[t] = 0;
        if (t == 0) { scnt = 0; gcnt = 0; }
        __syncthreads();
        #pragma unroll
        for (int i = 0; i < 4; ++i) pres[Ts[t + 256 * i]] = 1;
        __syncthreads();
        for (int s = t; s < N_SPECIES; s += 256) {
            if (pres[s]) {
                gm[s2g[s]] = 1;
                int idx = atomicAdd(&scnt, 1);
                wsI[OFF_LIST + idx] = s;
            }
        }
        __syncthreads();
        if (t < N_GENUS && gm[t]) atomicAdd(&gcnt, 1);
        __syncthreads();
        if (t == 0) { wsI[OFF_CNT] = scnt; ws[OFF_NVG] = (float)gcnt; }
        return;
    }

    // ---- projection waves ----
    int wave = blockIdx.x * 4 + (t >> 6);
    int lane = t & 63;

    float v;
    if (wave < N_SPECIES)                 v = sp[wave * EMB + lane];
    else if (wave < N_SPECIES + N_GENUS)  v = gp[(wave - N_SPECIES) * EMB + lane];
    else                                  v = X[(wave - N_SPECIES - N_GENUS) * EMB + lane];

    float ss = wave_sum(v * v);
    if (wave >= N_SPECIES + N_GENUS) {          // X rows: ||x||^2 + bf16 copy
        int row = wave - N_SPECIES - N_GENUS;
        xbf[row * BFSTRIDE + lane] = f2bf(v);
        if (lane == 0) ws[OFF_X2 + row] = ss;
        return;
    }

    float n  = fmaxf(__builtin_amdgcn_sqrtf(ss), 1e-5f);
    v *= fminf(1.0f, 2.3f * __builtin_amdgcn_rcpf(n));
    float n2 = fminf(n, 2.3f);
    float z  = SQRT_C * n2;
    float ez = __builtin_amdgcn_exp2f(-2.88539008f * z);   // exp(-2z)
    float th = (1.0f - ez) * __builtin_amdgcn_rcpf(1.0f + ez);
    float fac = th * __builtin_amdgcn_rcpf(z);
    float y = fac * v;
    float ss2 = wave_sum(y * y);
    float yn = fmaxf(__builtin_amdgcn_sqrtf(ss2), 1e-5f);
    const float maxnorm = (1.0f - 1e-3f) / SQRT_C;
    if (yn > maxnorm) {                         // wave-uniform
        y *= maxnorm * __builtin_amdgcn_rcpf(yn);
        ss2 = maxnorm * maxnorm;
    }
    if (wave < N_SPECIES) {
        ws[OFF_HYP_S + wave * EMB + lane] = y;
        sbf[wave * BFSTRIDE + lane] = f2bf(y);
        if (lane == 0) ws[OFF_S2 + wave] = ss2;
    } else {
        int g = wave - N_SPECIES;
        ws[OFF_HYP_G + g * EMB + lane] = y;
        if (lane == 0) ws[OFF_G2 + g] = ss2;
    }
}

// ---------------- K2: fused distance kernel + last-block final reduce ----------------
// blocks 0..1023: species 64x64 tile via MFMA bf16. blocks 1024..1279: genus (4 items each)
union SharedU {
    struct {
        uint4 xs[576];        // 64 rows x 72 bf16 (padded)
        uint4 ss[576];
        float x2s[64], s2s[64];
        int   tss[64];
        float red[8];
    } sp;
    struct {
        float hgt[EMB][61];   // transposed genus tile
        float hs[4][EMB];
        float g2s[64];
    } ge;
};

__global__ __launch_bounds__(256) void k_dist(
    const int* __restrict__ Ts, const int* __restrict__ s2g,
    float* __restrict__ ws, float* __restrict__ out)
{
    __shared__ SharedU sh;
    __shared__ int amLast;
    __shared__ float red2[16];
    int t = threadIdx.x;
    int bx = blockIdx.x;

    if (bx < 1024) {                     // ---------- species branch ----------
        int sBase = (bx & 63) * 64;
        int bBase = (bx >> 6) * 64;
        const unsigned short* xbf = (const unsigned short*)(ws + OFF_XBF);
        const unsigned short* sbf = (const unsigned short*)(ws + OFF_SBF);
        const uint4* srcx = (const uint4*)(xbf + bBase * BFSTRIDE);
        const uint4* srcs = (const uint4*)(sbf + sBase * BFSTRIDE);
        for (int i = t; i < 576; i += 256) { sh.sp.xs[i] = srcx[i]; sh.sp.ss[i] = srcs[i]; }
        if (t < 64) {
            sh.sp.x2s[t] = ws[OFF_X2 + bBase + t];
            sh.sp.s2s[t] = ws[OFF_S2 + sBase + t];
            sh.sp.tss[t] = Ts[bBase + t];
        }
        __syncthreads();

        int lane = t & 63, w = t >> 6;
        int nloc = lane & 15, quad = lane >> 4;
        const unsigned short* xs = (const unsigned short*)sh.sp.xs;
        const unsigned short* sb = (const unsigned short*)sh.sp.ss;

        f32x4 acc[4] = {{0.f,0.f,0.f,0.f},{0.f,0.f,0.f,0.f},{0.f,0.f,0.f,0.f},{0.f,0.f,0.f,0.f}};
        #pragma unroll
        for (int k0 = 0; k0 < EMB; k0 += 32) {
            bf16x8 a = *(const bf16x8*)(xs + (16 * w + nloc) * BFSTRIDE + k0 + quad * 8);
            #pragma unroll
            for (int jt = 0; jt < 4; ++jt) {
                bf16x8 b = *(const bf16x8*)(sb + (16 * jt + nloc) * BFSTRIDE + k0 + quad * 8);
                acc[jt] = __builtin_amdgcn_mfma_f32_16x16x32_bf16(a, b, acc[jt], 0, 0, 0);
            }
        }

        // C/D layout: col = lane&15, row = quad*4 + reg (verified round 4: absmax 0)
        float pos = 0.0f, neg = 0.0f;
        #pragma unroll
        for (int jt = 0; jt < 4; ++jt) {
            int sl = 16 * jt + nloc;
            float y2 = sh.sp.s2s[sl];
            #pragma unroll
            for (int r = 0; r < 4; ++r) {
                int m = 16 * w + quad * 4 + r;
                float d, lterm;
                pair_terms(-acc[jt][r], sh.sp.x2s[m], y2, d, lterm);
                if (sh.sp.tss[m] == sBase + sl) pos += d + lterm;   // softplus(d)=d+softplus(-d)
                else                            neg += lterm;
            }
        }
        pos = wave_sum(pos);
        neg = wave_sum(neg);
        if (lane == 0) { sh.sp.red[2 * w] = pos; sh.sp.red[2 * w + 1] = neg; }
        __syncthreads();
        if (t == 0) {
            float2 o;
            o.x = sh.sp.red[0] + sh.sp.red[2] + sh.sp.red[4] + sh.sp.red[6];
            o.y = sh.sp.red[1] + sh.sp.red[3] + sh.sp.red[5] + sh.sp.red[7];
            reinterpret_cast<float2*>(ws + OFF_SPART)[bx] = o;
        }
    } else {                             // ---------- genus branch ----------
        const int* wsI = (const int*)ws;
        int cnt  = wsI[OFF_CNT];
        int w    = t >> 6, lane = t & 63;
        int item = (bx - 1024) * 4 + w;
        int s    = (item < cnt) ? wsI[OFF_LIST + item] : -1;

        for (int idx = t; idx < N_GENUS * EMB; idx += 256)
            sh.ge.hgt[idx & 63][idx >> 6] = ws[OFF_HYP_G + idx];
        if (t < 64) sh.ge.g2s[t] = (t < N_GENUS) ? ws[OFF_G2 + t] : 0.0f;
        if (s >= 0) sh.ge.hs[w][lane] = ws[OFF_HYP_S + s * EMB + lane];
        __syncthreads();

        float pos = 0.0f, neg = 0.0f;
        if (s >= 0 && lane < N_GENUS) {
            float dot = 0.0f;
            #pragma unroll
            for (int k = 0; k < EMB; ++k) dot = fmaf(sh.ge.hs[w][k], sh.ge.hgt[k][lane], dot);
            float d, lterm;
            pair_terms(-dot, ws[OFF_S2 + s], sh.ge.g2s[lane], d, lterm);
            if (s2g[s] == lane) pos = d + lterm;
            else                neg = lterm;
        }
        pos = wave_sum(pos);
        neg = wave_sum(neg);
        if (lane == 0) {
            float2 o; o.x = pos; o.y = neg;
            reinterpret_cast<float2*>(ws + OFF_GPART)[item] = o;
        }
    }

    // ---------- two-level done-counter; last block reduces partials ----------
    int* ctrI = (int*)ws + OFF_CTR;
    __threadfence();                     // release: push partial stores device-visible
    __syncthreads();
    if (t == 0) {
        int last = 0;
        int grp = bx / 20;               // 64 groups x 20 blocks
        int v = atomicAdd(&ctrI[grp * 16], 1);
        if (v == 19) {
            int w2 = atomicAdd(&ctrI[64 * 16], 1);
            last = (w2 == 63);
        }
        amLast = last;
    }
    __syncthreads();
    if (amLast) {
        __threadfence();                 // acquire: invalidate stale L1/L2 partials
        const float2* spp = reinterpret_cast<const float2*>(ws + OFF_SPART);
        const float2* gpp = reinterpret_cast<const float2*>(ws + OFF_GPART);
        float ps = 0.0f, ns = 0.0f, pg = 0.0f, ng = 0.0f;
        for (int i = t; i < NB; i += 256) {
            float2 a = spp[i]; ps += a.x; ns += a.y;
            float2 b = gpp[i]; pg += b.x; ng += b.y;
        }
        ps = wave_sum(ps); ns = wave_sum(ns); pg = wave_sum(pg); ng = wave_sum(ng);
        int w = t >> 6;
        if ((t & 63) == 0) { red2[4*w] = ps; red2[4*w+1] = ns; red2[4*w+2] = pg; red2[4*w+3] = ng; }
        __syncthreads();
        if (t == 0) {
            ps = red2[0] + red2[4] + red2[8]  + red2[12];
            ns = red2[1] + red2[5] + red2[9]  + red2[13];
            pg = red2[2] + red2[6] + red2[10] + red2[14];
            ng = red2[3] + red2[7] + red2[11] + red2[15];
            const int* wsI = (const int*)ws;
            float nvs = fmaxf((float)wsI[OFF_CNT], 1.0f);
            float nvg = fmaxf(ws[OFF_NVG], 1.0f);
            out[0] = ps / nvs + ns / (float)N_SPECIES + pg / nvg + ng / (float)N_GENUS;
        }
    }
}

extern "C" void kernel_launch(void* const* d_in, const int* in_sizes, int n_in,
                              void* d_out, int out_size, void* d_ws, size_t ws_size,
                              hipStream_t stream) {
    const float* X   = (const float*)d_in[0];
    const int*   Ts  = (const int*)d_in[1];
    // d_in[2] = T_genus: unused by the reference loss
    const int*   s2g = (const int*)d_in[3];
    const float* gp  = (const float*)d_in[4];
    const float* sp  = (const float*)d_in[5];
    float* ws  = (float*)d_ws;
    float* out = (float*)d_out;

    k_prep<<<1296, 256, 0, stream>>>(X, Ts, s2g, gp, sp, ws);
    k_dist<<<1280, 256, 0, stream>>>(Ts, s2g, ws, out);
}

// Round 6
// 80.825 us; speedup vs baseline: 1.9142x; 1.9142x over previous
//
#include <hip/hip_runtime.h>
#include <math.h>

// ---------------- problem constants ----------------
constexpr float C_CURV = 0.1f;
constexpr float SQRT_C = 0.31622776601683794f;        // sqrt(0.1)

constexpr int N_GENUS   = 60;
constexpr int N_SPECIES = 4096;
constexpr int NB        = 1024;   // batch
constexpr int EMB       = 64;

// ---------------- workspace layout (floats) ----------------
constexpr int OFF_HYP_S = 0;                               // 4096*64 fp32
constexpr int OFF_HYP_G = OFF_HYP_S + N_SPECIES * EMB;     // 60*64
constexpr int OFF_S2    = OFF_HYP_G + N_GENUS * EMB;       // 4096
constexpr int OFF_G2    = OFF_S2 + N_SPECIES;              // 64 (60 used)
constexpr int OFF_X2    = OFF_G2 + 64;                     // 1024
constexpr int OFF_CNT   = OFF_X2 + NB;                     // 1 int: #present species (= nvs)
constexpr int OFF_NVG   = OFF_CNT + 1;                     // 1 float: #valid genera
// 64 spread accumulator lines, 16 floats (64B) apart. slots: 0=pos_sp 1=neg_sp 2=pos_g 3=neg_g
constexpr int OFF_ACCL  = ((OFF_CNT + 2 + 15) / 16) * 16;  // 64*16 floats
// done-counters: 64 group counters spread 64B apart + 1 level-2 counter
constexpr int OFF_CTR   = OFF_ACCL + 64 * 16;              // 65*16 ints
constexpr int OFF_LIST  = OFF_CTR + 65 * 16;               // 1024 ints compact present list
// bf16 copies, padded row stride 72 ushorts (16B-aligned rows)
constexpr int OFF_XBF   = ((OFF_LIST + NB + 3) / 4) * 4;   // 1024*72 ushort
constexpr int OFF_SBF   = OFF_XBF + NB * 72 / 2;           // 4096*72 ushort
constexpr int BFSTRIDE  = 72;

typedef short  bf16x8 __attribute__((ext_vector_type(8)));
typedef float  f32x4  __attribute__((ext_vector_type(4)));

// ---------------- helpers ----------------
__device__ __forceinline__ float wave_sum(float v) {
    #pragma unroll
    for (int off = 32; off; off >>= 1) v += __shfl_xor(v, off);
    return v;
}

__device__ __forceinline__ unsigned short f2bf(float f) {   // RNE f32 -> bf16
    unsigned int u = __builtin_bit_cast(unsigned int, f);
    u += 0x7FFFu + ((u >> 16) & 1u);
    return (unsigned short)(u >> 16);
}

// d = 2/sqrt(c)*atanh(arg); sp_neg = softplus(-d). u=(1-arg)/(1+arg), L=log2(u):
// d = -(ln2/sqrt(c))*L, exp(-d) = exp2(L/sqrt(c)). Native HW transcendentals only.
__device__ __forceinline__ void pair_terms(float dot_ay, float a2, float y2,
                                           float& d, float& sp_neg) {
    float ca   = fmaf(2.0f * C_CURV, dot_ay, fmaf(C_CURV, y2, 1.0f));
    float cy   = fmaf(-C_CURV, a2, 1.0f);
    float num2 = fmaf(ca * ca, a2, fmaf(2.0f * ca * cy, dot_ay, cy * cy * y2));
    float den  = fmaf(2.0f * C_CURV, dot_ay, fmaf(C_CURV * C_CURV, a2 * y2, 1.0f));
    float arg  = SQRT_C * __builtin_amdgcn_sqrtf(fmaxf(num2, 0.0f))
                        * __builtin_amdgcn_rcpf(fmaxf(fabsf(den), 1e-15f));
    arg = fminf(arg, 1.0f - 1e-5f);
    float u = (1.0f - arg) * __builtin_amdgcn_rcpf(1.0f + arg);
    float L = __builtin_amdgcn_logf(u);                    // log2(u) <= 0
    d       = -2.19201176f * L;
    float e = __builtin_amdgcn_exp2f(3.16227766f * L);     // exp(-d)
    sp_neg  = 0.69314718f * __builtin_amdgcn_logf(1.0f + e);
}

// ---------------- K1: fused prep ----------------
// blocks 0..1294: projection waves; block 1295: mask/list/counts + zero accum/counters
__global__ __launch_bounds__(256) void k_prep(
    const float* __restrict__ X, const int* __restrict__ Ts,
    const int* __restrict__ s2g, const float* __restrict__ gp,
    const float* __restrict__ sp, float* __restrict__ ws)
{
    __shared__ unsigned char pres[N_SPECIES];
    __shared__ unsigned char gm[64];
    __shared__ int scnt, gcnt;

    int t = threadIdx.x;
    unsigned short* xbf = (unsigned short*)(ws + OFF_XBF);
    unsigned short* sbf = (unsigned short*)(ws + OFF_SBF);

    if (blockIdx.x == 1295) {           // ---- mask block ----
        int* wsI = (int*)ws;
        for (int i = t; i < 64 * 16; i += 256) ws[OFF_ACCL + i] = 0.0f;   // zero accum lines
        for (int i = t; i < 65 * 16; i += 256) wsI[OFF_CTR + i] = 0;      // zero done-counters
        for (int s = t; s < N_SPECIES; s += 256) pres[s] = 0;
        if (t < 64) gm[t] = 0;
        if (t == 0) { scnt = 0; gcnt = 0; }
        __syncthreads();
        #pragma unroll
        for (int i = 0; i < 4; ++i) pres[Ts[t + 256 * i]] = 1;
        __syncthreads();
        for (int s = t; s < N_SPECIES; s += 256) {
            if (pres[s]) {
                gm[s2g[s]] = 1;
                int idx = atomicAdd(&scnt, 1);
                wsI[OFF_LIST + idx] = s;
            }
        }
        __syncthreads();
        if (t < N_GENUS && gm[t]) atomicAdd(&gcnt, 1);
        __syncthreads();
        if (t == 0) { wsI[OFF_CNT] = scnt; ws[OFF_NVG] = (float)gcnt; }
        return;
    }

    // ---- projection waves ----
    int wave = blockIdx.x * 4 + (t >> 6);
    int lane = t & 63;

    float v;
    if (wave < N_SPECIES)                 v = sp[wave * EMB + lane];
    else if (wave < N_SPECIES + N_GENUS)  v = gp[(wave - N_SPECIES) * EMB + lane];
    else                                  v = X[(wave - N_SPECIES - N_GENUS) * EMB + lane];

    float ss = wave_sum(v * v);
    if (wave >= N_SPECIES + N_GENUS) {          // X rows: ||x||^2 + bf16 copy
        int row = wave - N_SPECIES - N_GENUS;
        xbf[row * BFSTRIDE + lane] = f2bf(v);
        if (lane == 0) ws[OFF_X2 + row] = ss;
        return;
    }

    float n  = fmaxf(__builtin_amdgcn_sqrtf(ss), 1e-5f);
    v *= fminf(1.0f, 2.3f * __builtin_amdgcn_rcpf(n));
    float n2 = fminf(n, 2.3f);
    float z  = SQRT_C * n2;
    float ez = __builtin_amdgcn_exp2f(-2.88539008f * z);   // exp(-2z)
    float th = (1.0f - ez) * __builtin_amdgcn_rcpf(1.0f + ez);
    float fac = th * __builtin_amdgcn_rcpf(z);
    float y = fac * v;
    float ss2 = wave_sum(y * y);
    float yn = fmaxf(__builtin_amdgcn_sqrtf(ss2), 1e-5f);
    const float maxnorm = (1.0f - 1e-3f) / SQRT_C;
    if (yn > maxnorm) {                         // wave-uniform
        y *= maxnorm * __builtin_amdgcn_rcpf(yn);
        ss2 = maxnorm * maxnorm;
    }
    if (wave < N_SPECIES) {
        ws[OFF_HYP_S + wave * EMB + lane] = y;
        sbf[wave * BFSTRIDE + lane] = f2bf(y);
        if (lane == 0) ws[OFF_S2 + wave] = ss2;
    } else {
        int g = wave - N_SPECIES;
        ws[OFF_HYP_G + g * EMB + lane] = y;
        if (lane == 0) ws[OFF_G2 + g] = ss2;
    }
}

// ---------------- K2: fused distance kernel, atomic-only last-block finish ----------------
// blocks 0..1023: species 64x64 tile via MFMA bf16. blocks 1024..1279: genus (4 items each).
// NO __threadfence anywhere (round-5 lesson: per-block buffer_wbl2 costs ~80 us).
// All cross-block data flows through device atomics (coherent at Infinity Cache).
union SharedU {
    struct {
        uint4 xs[576];        // 64 rows x 72 bf16 (padded)
        uint4 ss[576];
        float x2s[64], s2s[64];
        int   tss[64];
    } sp;
    struct {
        float hgt[EMB][61];   // transposed genus tile
        float hs[4][EMB];
        float g2s[64];
    } ge;
};

__global__ __launch_bounds__(256) void k_dist(
    const int* __restrict__ Ts, const int* __restrict__ s2g,
    float* __restrict__ ws, float* __restrict__ out)
{
    __shared__ SharedU sh;
    __shared__ float redB[8];
    __shared__ float red2[16];
    __shared__ int amLast;
    int t = threadIdx.x;
    int bx = blockIdx.x;
    int lane = t & 63, w = t >> 6;
    float pos = 0.0f, neg = 0.0f;

    if (bx < 1024) {                     // ---------- species branch ----------
        int sBase = (bx & 63) * 64;
        int bBase = (bx >> 6) * 64;
        const unsigned short* xbf = (const unsigned short*)(ws + OFF_XBF);
        const unsigned short* sbf = (const unsigned short*)(ws + OFF_SBF);
        const uint4* srcx = (const uint4*)(xbf + bBase * BFSTRIDE);
        const uint4* srcs = (const uint4*)(sbf + sBase * BFSTRIDE);
        for (int i = t; i < 576; i += 256) { sh.sp.xs[i] = srcx[i]; sh.sp.ss[i] = srcs[i]; }
        if (t < 64) {
            sh.sp.x2s[t] = ws[OFF_X2 + bBase + t];
            sh.sp.s2s[t] = ws[OFF_S2 + sBase + t];
            sh.sp.tss[t] = Ts[bBase + t];
        }
        __syncthreads();

        int nloc = lane & 15, quad = lane >> 4;
        const unsigned short* xs = (const unsigned short*)sh.sp.xs;
        const unsigned short* sb = (const unsigned short*)sh.sp.ss;

        f32x4 acc[4] = {{0.f,0.f,0.f,0.f},{0.f,0.f,0.f,0.f},{0.f,0.f,0.f,0.f},{0.f,0.f,0.f,0.f}};
        #pragma unroll
        for (int k0 = 0; k0 < EMB; k0 += 32) {
            bf16x8 a = *(const bf16x8*)(xs + (16 * w + nloc) * BFSTRIDE + k0 + quad * 8);
            #pragma unroll
            for (int jt = 0; jt < 4; ++jt) {
                bf16x8 b = *(const bf16x8*)(sb + (16 * jt + nloc) * BFSTRIDE + k0 + quad * 8);
                acc[jt] = __builtin_amdgcn_mfma_f32_16x16x32_bf16(a, b, acc[jt], 0, 0, 0);
            }
        }

        // C/D layout: col = lane&15, row = quad*4 + reg (verified: absmax 0 in rounds 4/5)
        #pragma unroll
        for (int jt = 0; jt < 4; ++jt) {
            int sl = 16 * jt + nloc;
            float y2 = sh.sp.s2s[sl];
            #pragma unroll
            for (int r = 0; r < 4; ++r) {
                int m = 16 * w + quad * 4 + r;
                float d, lterm;
                pair_terms(-acc[jt][r], sh.sp.x2s[m], y2, d, lterm);
                if (sh.sp.tss[m] == sBase + sl) pos += d + lterm;   // softplus(d)=d+softplus(-d)
                else                            neg += lterm;
            }
        }
    } else {                             // ---------- genus branch ----------
        const int* wsI = (const int*)ws;
        int cnt  = wsI[OFF_CNT];
        int item = (bx - 1024) * 4 + w;
        int s    = (item < cnt) ? wsI[OFF_LIST + item] : -1;

        for (int idx = t; idx < N_GENUS * EMB; idx += 256)
            sh.ge.hgt[idx & 63][idx >> 6] = ws[OFF_HYP_G + idx];
        if (t < 64) sh.ge.g2s[t] = (t < N_GENUS) ? ws[OFF_G2 + t] : 0.0f;
        if (s >= 0) sh.ge.hs[w][lane] = ws[OFF_HYP_S + s * EMB + lane];
        __syncthreads();

        if (s >= 0 && lane < N_GENUS) {
            float dot = 0.0f;
            #pragma unroll
            for (int k = 0; k < EMB; ++k) dot = fmaf(sh.ge.hs[w][k], sh.ge.hgt[k][lane], dot);
            float d, lterm;
            pair_terms(-dot, ws[OFF_S2 + s], sh.ge.g2s[lane], d, lterm);
            if (s2g[s] == lane) pos = d + lterm;
            else                neg = lterm;
        }
    }

    // ---------- block reduce -> spread atomic accumulate -> two-level done-counter ----------
    pos = wave_sum(pos);
    neg = wave_sum(neg);
    if (lane == 0) { redB[2 * w] = pos; redB[2 * w + 1] = neg; }
    __syncthreads();
    int* ctrI = (int*)ws + OFF_CTR;
    if (t == 0) {
        float bp = redB[0] + redB[2] + redB[4] + redB[6];
        float bn = redB[1] + redB[3] + redB[5] + redB[7];
        float* line = ws + OFF_ACCL + (bx & 63) * 16 + (bx < 1024 ? 0 : 2);
        atomicAdd(line + 0, bp);                 // device-scope, performed at IF$ (coherent)
        atomicAdd(line + 1, bn);
        __builtin_amdgcn_s_waitcnt(0);           // order: data atomics acked before counter
        int last = 0;
        int grp = bx / 20;                       // 64 groups x 20 blocks
        int v = atomicAdd(&ctrI[grp * 16], 1);
        if (v == 19) {
            int w2 = atomicAdd(&ctrI[64 * 16], 1);
            last = (w2 == 63);
        }
        amLast = last;
    }
    __syncthreads();
    if (amLast) {
        // read 64 lines x 4 slots via atomic read (add 0.0) — coherent, no stale L2
        float v = atomicAdd(ws + OFF_ACCL + (t >> 2) * 16 + (t & 3), 0.0f);
        int slot = t & 3;
        float s0 = wave_sum(slot == 0 ? v : 0.0f);
        float s1 = wave_sum(slot == 1 ? v : 0.0f);
        float s2 = wave_sum(slot == 2 ? v : 0.0f);
        float s3 = wave_sum(slot == 3 ? v : 0.0f);
        if (lane == 0) { red2[4*w] = s0; red2[4*w+1] = s1; red2[4*w+2] = s2; red2[4*w+3] = s3; }
        __syncthreads();
        if (t == 0) {
            float ps = red2[0] + red2[4] + red2[8]  + red2[12];
            float ns = red2[1] + red2[5] + red2[9]  + red2[13];
            float pg = red2[2] + red2[6] + red2[10] + red2[14];
            float ng = red2[3] + red2[7] + red2[11] + red2[15];
            const int* wsI = (const int*)ws;
            float nvs = fmaxf((float)wsI[OFF_CNT], 1.0f);
            float nvg = fmaxf(ws[OFF_NVG], 1.0f);
            out[0] = ps / nvs + ns / (float)N_SPECIES + pg / nvg + ng / (float)N_GENUS;
        }
    }
}

extern "C" void kernel_launch(void* const* d_in, const int* in_sizes, int n_in,
                              void* d_out, int out_size, void* d_ws, size_t ws_size,
                              hipStream_t stream) {
    const float* X   = (const float*)d_in[0];
    const int*   Ts  = (const int*)d_in[1];
    // d_in[2] = T_genus: unused by the reference loss
    const int*   s2g = (const int*)d_in[3];
    const float* gp  = (const float*)d_in[4];
    const float* sp  = (const float*)d_in[5];
    float* ws  = (float*)d_ws;
    float* out = (float*)d_out;

    k_prep<<<1296, 256, 0, stream>>>(X, Ts, s2g, gp, sp, ws);
    k_dist<<<1280, 256, 0, stream>>>(Ts, s2g, ws, out);
}

// Round 7
// 80.640 us; speedup vs baseline: 1.9186x; 1.0023x over previous
//
#include <hip/hip_runtime.h>
#include <math.h>

// ---------------- problem constants ----------------
constexpr float C_CURV = 0.1f;
constexpr float SQRT_C = 0.31622776601683794f;        // sqrt(0.1)

constexpr int N_GENUS   = 60;
constexpr int N_SPECIES = 4096;
constexpr int NB        = 1024;   // batch
constexpr int EMB       = 64;

// ---------------- workspace layout (floats) ----------------
constexpr int OFF_HYP_S = 0;                               // 4096*64 fp32
constexpr int OFF_HYP_G = OFF_HYP_S + N_SPECIES * EMB;     // 60*64
constexpr int OFF_S2    = OFF_HYP_G + N_GENUS * EMB;       // 4096
constexpr int OFF_G2    = OFF_S2 + N_SPECIES;              // 64 (60 used)
constexpr int OFF_X2    = OFF_G2 + 64;                     // 1024
constexpr int OFF_CNT   = OFF_X2 + NB;                     // 1 int: #present species (= nvs)
constexpr int OFF_NVG   = OFF_CNT + 1;                     // 1 float: #valid genera
// 64 spread accumulator lines, 16 floats (64B) apart. slots: 0=pos_sp 1=neg_sp 2=pos_g 3=neg_g
constexpr int OFF_ACCL  = ((OFF_CNT + 2 + 15) / 16) * 16;  // 64*16 floats
// done-counters: 64 group counters spread 64B apart + 1 level-2 counter
constexpr int OFF_CTR   = OFF_ACCL + 64 * 16;              // 65*16 ints
constexpr int OFF_LIST  = OFF_CTR + 65 * 16;               // 1024 ints compact present list
// bf16 copies, padded row stride 72 ushorts (16B-aligned rows)
constexpr int OFF_XBF   = ((OFF_LIST + NB + 3) / 4) * 4;   // 1024*72 ushort
constexpr int OFF_SBF   = OFF_XBF + NB * 72 / 2;           // 4096*72 ushort
constexpr int BFSTRIDE  = 72;

typedef short  bf16x8 __attribute__((ext_vector_type(8)));
typedef float  f32x4  __attribute__((ext_vector_type(4)));

// ---------------- helpers ----------------
__device__ __forceinline__ float wave_sum(float v) {
    #pragma unroll
    for (int off = 32; off; off >>= 1) v += __shfl_xor(v, off);
    return v;
}

__device__ __forceinline__ unsigned short f2bf(float f) {   // RNE f32 -> bf16
    unsigned int u = __builtin_bit_cast(unsigned int, f);
    u += 0x7FFFu + ((u >> 16) & 1u);
    return (unsigned short)(u >> 16);
}

// d = 2/sqrt(c)*atanh(arg), arg = clip(sqrt(c)*||num||/|den|, 0, 1-1e-5); sp_neg = softplus(-d).
// Single-rcp form: s = sqrt(c)*||num||, u = (1-arg)/(1+arg) = (|den|-s)/(|den|+s);
// clamp arg<=1-1e-5  <=>  u >= 1e-5/(2-1e-5) = 5.000025e-6. L = log2(u):
// d = -(ln2/sqrt(c))*L; exp(-d) = exp2(L/sqrt(c)). 5 native transcendentals total.
__device__ __forceinline__ void pair_terms(float dot_ay, float a2, float y2,
                                           float& d, float& sp_neg) {
    float ca   = fmaf(2.0f * C_CURV, dot_ay, fmaf(C_CURV, y2, 1.0f));
    float cy   = fmaf(-C_CURV, a2, 1.0f);
    float num2 = fmaf(ca * ca, a2, fmaf(2.0f * ca * cy, dot_ay, cy * cy * y2));
    float den  = fabsf(fmaf(2.0f * C_CURV, dot_ay, fmaf(C_CURV * C_CURV, a2 * y2, 1.0f)));
    float s    = SQRT_C * __builtin_amdgcn_sqrtf(fmaxf(num2, 0.0f));
    float u    = fmaxf((den - s) * __builtin_amdgcn_rcpf(den + s), 5.000025e-6f);
    float L    = __builtin_amdgcn_logf(u);                 // log2(u) <= 0
    d          = -2.19201176f * L;
    float e    = __builtin_amdgcn_exp2f(3.16227766f * L);  // exp(-d)
    sp_neg     = 0.69314718f * __builtin_amdgcn_logf(1.0f + e);
}

// ---------------- K1: fused prep ----------------
// blocks 0..1294: projection waves; block 1295: mask/list/counts + zero accum/counters
__global__ __launch_bounds__(256) void k_prep(
    const float* __restrict__ X, const int* __restrict__ Ts,
    const int* __restrict__ s2g, const float* __restrict__ gp,
    const float* __restrict__ sp, float* __restrict__ ws)
{
    __shared__ unsigned char pres[N_SPECIES];
    __shared__ unsigned char gm[64];
    __shared__ int scnt, gcnt;

    int t = threadIdx.x;
    unsigned short* xbf = (unsigned short*)(ws + OFF_XBF);
    unsigned short* sbf = (unsigned short*)(ws + OFF_SBF);

    if (blockIdx.x == 1295) {           // ---- mask block ----
        int* wsI = (int*)ws;
        for (int i = t; i < 64 * 16; i += 256) ws[OFF_ACCL + i] = 0.0f;   // zero accum lines
        for (int i = t; i < 65 * 16; i += 256) wsI[OFF_CTR + i] = 0;      // zero done-counters
        for (int s = t; s < N_SPECIES; s += 256) pres[s] = 0;
        if (t < 64) gm[t] = 0;
        if (t == 0) { scnt = 0; gcnt = 0; }
        __syncthreads();
        #pragma unroll
        for (int i = 0; i < 4; ++i) pres[Ts[t + 256 * i]] = 1;
        __syncthreads();
        for (int s = t; s < N_SPECIES; s += 256) {
            if (pres[s]) {
                gm[s2g[s]] = 1;
                int idx = atomicAdd(&scnt, 1);
                wsI[OFF_LIST + idx] = s;
            }
        }
        __syncthreads();
        if (t < N_GENUS && gm[t]) atomicAdd(&gcnt, 1);
        __syncthreads();
        if (t == 0) { wsI[OFF_CNT] = scnt; ws[OFF_NVG] = (float)gcnt; }
        return;
    }

    // ---- projection waves ----
    int wave = blockIdx.x * 4 + (t >> 6);
    int lane = t & 63;

    float v;
    if (wave < N_SPECIES)                 v = sp[wave * EMB + lane];
    else if (wave < N_SPECIES + N_GENUS)  v = gp[(wave - N_SPECIES) * EMB + lane];
    else                                  v = X[(wave - N_SPECIES - N_GENUS) * EMB + lane];

    float ss = wave_sum(v * v);
    if (wave >= N_SPECIES + N_GENUS) {          // X rows: ||x||^2 + bf16 copy
        int row = wave - N_SPECIES - N_GENUS;
        xbf[row * BFSTRIDE + lane] = f2bf(v);
        if (lane == 0) ws[OFF_X2 + row] = ss;
        return;
    }

    float n  = fmaxf(__builtin_amdgcn_sqrtf(ss), 1e-5f);
    v *= fminf(1.0f, 2.3f * __builtin_amdgcn_rcpf(n));
    float n2 = fminf(n, 2.3f);
    float z  = SQRT_C * n2;
    float ez = __builtin_amdgcn_exp2f(-2.88539008f * z);   // exp(-2z)
    float th = (1.0f - ez) * __builtin_amdgcn_rcpf(1.0f + ez);
    float fac = th * __builtin_amdgcn_rcpf(z);
    float y = fac * v;
    float ss2 = wave_sum(y * y);
    float yn = fmaxf(__builtin_amdgcn_sqrtf(ss2), 1e-5f);
    const float maxnorm = (1.0f - 1e-3f) / SQRT_C;
    if (yn > maxnorm) {                         // wave-uniform
        y *= maxnorm * __builtin_amdgcn_rcpf(yn);
        ss2 = maxnorm * maxnorm;
    }
    if (wave < N_SPECIES) {
        ws[OFF_HYP_S + wave * EMB + lane] = y;
        sbf[wave * BFSTRIDE + lane] = f2bf(y);
        if (lane == 0) ws[OFF_S2 + wave] = ss2;
    } else {
        int g = wave - N_SPECIES;
        ws[OFF_HYP_G + g * EMB + lane] = y;
        if (lane == 0) ws[OFF_G2 + g] = ss2;
    }
}

// ---------------- K2: fused distance kernel, atomic-only last-block finish ----------------
// blocks 0..1023: species 64x64 tile via MFMA bf16. blocks 1024..1279: genus (4 items each).
// NO __threadfence anywhere (round-5 lesson: 1280 per-block buffer_wbl2 cost ~80 us).
// All cross-block data flows through device atomics (coherent at Infinity Cache).
union SharedU {
    struct {
        uint4 xs[576];        // 64 rows x 72 bf16 (padded)
        uint4 ss[576];
        float x2s[64], s2s[64];
        int   tss[64];
    } sp;
    struct {
        float hgt[EMB][61];   // transposed genus tile
        float hs[4][EMB];
        float g2s[64];
    } ge;
};

__global__ __launch_bounds__(256) void k_dist(
    const int* __restrict__ Ts, const int* __restrict__ s2g,
    float* __restrict__ ws, float* __restrict__ out)
{
    __shared__ SharedU sh;
    __shared__ float redB[8];
    __shared__ float red2[16];
    __shared__ int amLast;
    int t = threadIdx.x;
    int bx = blockIdx.x;
    int lane = t & 63, w = t >> 6;
    float pos = 0.0f, neg = 0.0f;

    if (bx < 1024) {                     // ---------- species branch ----------
        int sBase = (bx & 63) * 64;
        int bBase = (bx >> 6) * 64;
        const unsigned short* xbf = (const unsigned short*)(ws + OFF_XBF);
        const unsigned short* sbf = (const unsigned short*)(ws + OFF_SBF);
        const uint4* srcx = (const uint4*)(xbf + bBase * BFSTRIDE);
        const uint4* srcs = (const uint4*)(sbf + sBase * BFSTRIDE);
        for (int i = t; i < 576; i += 256) { sh.sp.xs[i] = srcx[i]; sh.sp.ss[i] = srcs[i]; }
        if (t < 64) {
            sh.sp.x2s[t] = ws[OFF_X2 + bBase + t];
            sh.sp.s2s[t] = ws[OFF_S2 + sBase + t];
            sh.sp.tss[t] = Ts[bBase + t];
        }
        __syncthreads();

        int nloc = lane & 15, quad = lane >> 4;
        const unsigned short* xs = (const unsigned short*)sh.sp.xs;
        const unsigned short* sb = (const unsigned short*)sh.sp.ss;

        f32x4 acc[4] = {{0.f,0.f,0.f,0.f},{0.f,0.f,0.f,0.f},{0.f,0.f,0.f,0.f},{0.f,0.f,0.f,0.f}};
        #pragma unroll
        for (int k0 = 0; k0 < EMB; k0 += 32) {
            bf16x8 a = *(const bf16x8*)(xs + (16 * w + nloc) * BFSTRIDE + k0 + quad * 8);
            #pragma unroll
            for (int jt = 0; jt < 4; ++jt) {
                bf16x8 b = *(const bf16x8*)(sb + (16 * jt + nloc) * BFSTRIDE + k0 + quad * 8);
                acc[jt] = __builtin_amdgcn_mfma_f32_16x16x32_bf16(a, b, acc[jt], 0, 0, 0);
            }
        }

        // C/D layout: col = lane&15, row = quad*4 + reg (verified: absmax 0 in rounds 4-6)
        #pragma unroll
        for (int jt = 0; jt < 4; ++jt) {
            int sl = 16 * jt + nloc;
            float y2 = sh.sp.s2s[sl];
            #pragma unroll
            for (int r = 0; r < 4; ++r) {
                int m = 16 * w + quad * 4 + r;
                float d, lterm;
                pair_terms(-acc[jt][r], sh.sp.x2s[m], y2, d, lterm);
                if (sh.sp.tss[m] == sBase + sl) pos += d + lterm;   // softplus(d)=d+softplus(-d)
                else                            neg += lterm;
            }
        }
    } else {                             // ---------- genus branch ----------
        const int* wsI = (const int*)ws;
        int cnt  = wsI[OFF_CNT];
        int item = (bx - 1024) * 4 + w;
        int s    = (item < cnt) ? wsI[OFF_LIST + item] : -1;

        for (int idx = t; idx < N_GENUS * EMB; idx += 256)
            sh.ge.hgt[idx & 63][idx >> 6] = ws[OFF_HYP_G + idx];
        if (t < 64) sh.ge.g2s[t] = (t < N_GENUS) ? ws[OFF_G2 + t] : 0.0f;
        if (s >= 0) sh.ge.hs[w][lane] = ws[OFF_HYP_S + s * EMB + lane];
        __syncthreads();

        if (s >= 0 && lane < N_GENUS) {
            float dot = 0.0f;
            #pragma unroll
            for (int k = 0; k < EMB; ++k) dot = fmaf(sh.ge.hs[w][k], sh.ge.hgt[k][lane], dot);
            float d, lterm;
            pair_terms(-dot, ws[OFF_S2 + s], sh.ge.g2s[lane], d, lterm);
            if (s2g[s] == lane) pos = d + lterm;
            else                neg = lterm;
        }
    }

    // ---------- block reduce -> spread atomic accumulate -> two-level done-counter ----------
    pos = wave_sum(pos);
    neg = wave_sum(neg);
    if (lane == 0) { redB[2 * w] = pos; redB[2 * w + 1] = neg; }
    __syncthreads();
    int* ctrI = (int*)ws + OFF_CTR;
    if (t == 0) {
        float bp = redB[0] + redB[2] + redB[4] + redB[6];
        float bn = redB[1] + redB[3] + redB[5] + redB[7];
        float* line = ws + OFF_ACCL + (bx & 63) * 16 + (bx < 1024 ? 0 : 2);
        atomicAdd(line + 0, bp);                 // device-scope, performed at IF$ (coherent)
        atomicAdd(line + 1, bn);
        __builtin_amdgcn_s_waitcnt(0);           // order: data atomics acked before counter
        int last = 0;
        int grp = bx / 20;                       // 64 groups x 20 blocks
        int v = atomicAdd(&ctrI[grp * 16], 1);
        if (v == 19) {
            int w2 = atomicAdd(&ctrI[64 * 16], 1);
            last = (w2 == 63);
        }
        amLast = last;
    }
    __syncthreads();
    if (amLast) {
        // read 64 lines x 4 slots via atomic read (add 0.0) — coherent, no stale L2
        float v = atomicAdd(ws + OFF_ACCL + (t >> 2) * 16 + (t & 3), 0.0f);
        int slot = t & 3;
        float s0 = wave_sum(slot == 0 ? v : 0.0f);
        float s1 = wave_sum(slot == 1 ? v : 0.0f);
        float s2 = wave_sum(slot == 2 ? v : 0.0f);
        float s3 = wave_sum(slot == 3 ? v : 0.0f);
        if (lane == 0) { red2[4*w] = s0; red2[4*w+1] = s1; red2[4*w+2] = s2; red2[4*w+3] = s3; }
        __syncthreads();
        if (t == 0) {
            float ps = red2[0] + red2[4] + red2[8]  + red2[12];
            float ns = red2[1] + red2[5] + red2[9]  + red2[13];
            float pg = red2[2] + red2[6] + red2[10] + red2[14];
            float ng = red2[3] + red2[7] + red2[11] + red2[15];
            const int* wsI = (const int*)ws;
            float nvs = fmaxf((float)wsI[OFF_CNT], 1.0f);
            float nvg = fmaxf(ws[OFF_NVG], 1.0f);
            out[0] = ps / nvs + ns / (float)N_SPECIES + pg / nvg + ng / (float)N_GENUS;
        }
    }
}

extern "C" void kernel_launch(void* const* d_in, const int* in_sizes, int n_in,
                              void* d_out, int out_size, void* d_ws, size_t ws_size,
                              hipStream_t stream) {
    const float* X   = (const float*)d_in[0];
    const int*   Ts  = (const int*)d_in[1];
    // d_in[2] = T_genus: unused by the reference loss
    const int*   s2g = (const int*)d_in[3];
    const float* gp  = (const float*)d_in[4];
    const float* sp  = (const float*)d_in[5];
    float* ws  = (float*)d_ws;
    float* out = (float*)d_out;

    k_prep<<<1296, 256, 0, stream>>>(X, Ts, s2g, gp, sp, ws);
    k_dist<<<1280, 256, 0, stream>>>(Ts, s2g, ws, out);
}